// Round 12
// baseline (307.786 us; speedup 1.0000x reference)
//
#include <hip/hip_runtime.h>
#include <math.h>

#define NN 10000
#define EE 160000
#define FI 32
#define DE 8
#define HD 64
#define TT 3
#define OD 12

typedef float f32x2  __attribute__((ext_vector_type(2)));
typedef float f32x16 __attribute__((ext_vector_type(16)));

// ---------------- bulk zero (cnt, cursor only) ----------------

__global__ __launch_bounds__(256) void zero_k(float4* __restrict__ base, int n4) {
  for (int i = blockIdx.x * 256 + threadIdx.x; i < n4; i += gridDim.x * 256)
    base[i] = float4{0.f, 0.f, 0.f, 0.f};
}

// ---------------- CSR construction (pair-slot layout) ----------------
// Row i holds deg_i edges + 1 self loop in ceil((deg_i+1)/2) PAIR slots.
// Pair slot p stores two edges interleaved: ea_g[p*16 + d*2 + comp], comp in {0,1}.
// src_g stays linear: src_g[2*rp[i] + j] for row-local edge j.

__global__ __launch_bounds__(256) void hist_k(const int* __restrict__ ei, int* __restrict__ cnt) {
  int e = blockIdx.x * 256 + threadIdx.x;
  if (e < EE) atomicAdd(&cnt[ei[EE + e]], 1);
}

// rowptr2[i] = exclusive scan of (cnt[i]+2)>>1   (pair units)
__global__ __launch_bounds__(1024) void scan_k(const int* __restrict__ cnt, int* __restrict__ rowptr2) {
  __shared__ int wsum[16];
  const int tid = threadIdx.x, lane = tid & 63, wid = tid >> 6;
  const int i0 = tid * 10;
  int v[10];
  int tot = 0;
#pragma unroll
  for (int j = 0; j < 10; ++j) {
    int i = i0 + j;
    v[j] = (i < NN) ? ((cnt[i] + 2) >> 1) : 0;
    tot += v[j];
  }
  int s = tot;
#pragma unroll
  for (int o = 1; o < 64; o <<= 1) {
    int t = __shfl_up(s, o, 64);
    if (lane >= o) s += t;
  }
  if (lane == 63) wsum[wid] = s;
  __syncthreads();
  if (wid == 0) {
    int ws = (lane < 16) ? wsum[lane] : 0;
#pragma unroll
    for (int o = 1; o < 16; o <<= 1) {
      int t = __shfl_up(ws, o, 64);
      if (lane >= o) ws += t;
    }
    if (lane < 16) wsum[lane] = ws;
  }
  __syncthreads();
  int base = s - tot + (wid > 0 ? wsum[wid - 1] : 0);
  int run = 0;
#pragma unroll
  for (int j = 0; j < 10; ++j) {
    int i = i0 + j;
    if (i < NN) rowptr2[i] = base + run;
    run += v[j];
  }
  if (tid == 1023) rowptr2[NN] = base + run;
}

// scatter edges into pair-interleaved CSR order (plain stores, no fp atomics)
__global__ __launch_bounds__(256) void scatter_k(const int* __restrict__ ei, const int* __restrict__ rowptr2,
                                                 int* __restrict__ cursor, int* __restrict__ src_g,
                                                 const float* __restrict__ ea, float* __restrict__ ea_g) {
  int e = blockIdx.x * 256 + threadIdx.x;
  if (e >= EE) return;
  int s = ei[e], d = ei[EE + e];
  int rp = rowptr2[d];
  int j = atomicAdd(&cursor[d], 1);
  src_g[2 * rp + j] = s;
  float* dst = ea_g + ((size_t)(rp + (j >> 1)) * 16 + (j & 1));
  const float* srcp = ea + (size_t)e * DE;
#pragma unroll
  for (int dd = 0; dd < DE; ++dd) dst[2 * dd] = srcp[dd];
}

// self-loop slot (row-local edge index deg): mean of the row's edge attrs. One wave per node.
__global__ __launch_bounds__(256) void selfmean_k(const int* __restrict__ rowptr2, const int* __restrict__ cnt,
                                                  int* __restrict__ src_g, float* __restrict__ ea_g) {
  int n = blockIdx.x * 4 + (threadIdx.x >> 6);
  int lane = threadIdx.x & 63;
  if (n >= NN) return;
  int rp = rowptr2[n];
  int deg = cnt[n];
  int j = lane >> 3, dd = lane & 7;
  float s = 0.f;
  for (int base = 0; base < deg; base += 8) {
    int idx = base + j;
    if (idx < deg) s += ea_g[(size_t)(rp + (idx >> 1)) * 16 + (idx & 1) + 2 * dd];
  }
#pragma unroll
  for (int o = 8; o < 64; o <<= 1) s += __shfl_xor(s, o, 64);
  if (lane < 8)
    ea_g[(size_t)(rp + (deg >> 1)) * 16 + (deg & 1) + 2 * lane] = s / (float)(deg > 0 ? deg : 1);
  if (lane == 0) src_g[2 * rp + deg] = n;
}

// ---------------- node phase: xl/xr; 8 nodes per block; b128 LDS reads ----------------
// gridDim.y = 1 at t=0 (x-branch only; h==0 makes the h-branch constant), 2 otherwise.

__global__ __launch_bounds__(256) void node_k(const float* __restrict__ x_t, const float* __restrict__ h,
                                              const float* __restrict__ Wl_x, const float* __restrict__ bl_x,
                                              const float* __restrict__ Wr_x, const float* __restrict__ br_x,
                                              const float* __restrict__ Wl_h, const float* __restrict__ bl_h,
                                              const float* __restrict__ Wr_h, const float* __restrict__ br_h,
                                              float* __restrict__ xl, float* __restrict__ xr) {
  const int n0 = blockIdx.x * 8;
  const int b = blockIdx.y;
  const int k = threadIdx.x >> 6;
  const int lane = threadIdx.x & 63;
  const int K = b ? HD : FI;
  const int ksh = b ? 6 : 5;
  __shared__ float inp[8][HD];   // row-major: one row per node
  const float* srcbase = b ? (h + (size_t)n0 * HD) : (x_t + (size_t)n0 * FI);
  for (int idx = threadIdx.x; idx < 8 * K; idx += 256)
    inp[idx >> ksh][idx & (K - 1)] = srcbase[idx];
  __syncthreads();

  const float* Wl = (b ? Wl_h : Wl_x) + (size_t)k * K * HD;
  const float* Wr = (b ? Wr_h : Wr_x) + (size_t)k * K * HD;
  const float blv = (b ? bl_h : bl_x)[k * HD + lane];
  const float brv = (b ? br_h : br_x)[k * HD + lane];
  float al[8], ar[8];
#pragma unroll
  for (int j = 0; j < 8; ++j) { al[j] = blv; ar[j] = brv; }
  for (int kk = 0; kk < K; kk += 4) {
    float wl[4], wr[4];
#pragma unroll
    for (int q = 0; q < 4; ++q) {
      wl[q] = Wl[(kk + q) * HD + lane];
      wr[q] = Wr[(kk + q) * HD + lane];
    }
#pragma unroll
    for (int j = 0; j < 8; ++j) {
      const float4 v4 = *reinterpret_cast<const float4*>(&inp[j][kk]);  // LDS b128 broadcast
      al[j] = fmaf(v4.x, wl[0], al[j]); ar[j] = fmaf(v4.x, wr[0], ar[j]);
      al[j] = fmaf(v4.y, wl[1], al[j]); ar[j] = fmaf(v4.y, wr[1], ar[j]);
      al[j] = fmaf(v4.z, wl[2], al[j]); ar[j] = fmaf(v4.z, wr[2], ar[j]);
      al[j] = fmaf(v4.w, wl[3], al[j]); ar[j] = fmaf(v4.w, wr[3], ar[j]);
    }
  }
#pragma unroll
  for (int j = 0; j < 8; ++j) {
    size_t o = (((size_t)b * 4 + k) * NN + (n0 + j)) * HD + lane;
    xl[o] = al[j];
    xr[o] = ar[j];
  }
}

// ---------------- edge phase: one wave per (conv, node); PAIRED packed-FP32 math ----------------
// Each pair slot provides (ea0[d],ea1[d]) in adjacent uniform SGPRs -> v_pk_fma_f32 dot.
// Reduce = per-component DPP row_ror chain + permlane16_swap (pure VALU, no LDS).

template <int CTRL>
__device__ __forceinline__ f32x2 dpp_ror_add2(f32x2 t) {
  int rx = __builtin_amdgcn_update_dpp(0, __float_as_int(t.x), CTRL, 0xF, 0xF, true);
  int ry = __builtin_amdgcn_update_dpp(0, __float_as_int(t.y), CTRL, 0xF, 0xF, true);
  t.x += __int_as_float(rx);
  t.y += __int_as_float(ry);
  return t;
}

__device__ __forceinline__ float xor16_add(float t) {
  float a = t, b = t;
  asm volatile("" : "+v"(b));   // keep b in its own register
  asm("v_permlane16_swap_b32 %0, %1" : "+v"(a), "+v"(b));
  return a + b;                 // head sum broadcast to all 32 lanes
}

__device__ __forceinline__ f32x2 reduce32_2(f32x2 t) {
  t = dpp_ror_add2<0x128>(t);
  t = dpp_ror_add2<0x124>(t);
  t = dpp_ror_add2<0x122>(t);
  t = dpp_ror_add2<0x121>(t);
  t.x = xor16_add(t.x);
  t.y = xor16_add(t.y);
  return t;
}

__device__ __forceinline__ float exp2_raw(float x) {
  float r;
  asm("v_exp_f32 %0, %1" : "=v"(r) : "v"(x));
  return r;
}

// one PAIR of edges (packed over components)
#define PAIR(j2) do { \
  const f32x16 E = pea[rp0 + (j2)]; \
  const int2 sp = *reinterpret_cast<const int2*>(src_g + base2 + 2 * (j2)); \
  const float x0 = xlb[(size_t)sp.x * HD + lane]; \
  const float x1 = xlb[(size_t)sp.y * HD + lane]; \
  f32x2 t = (f32x2){x0 + xrv, x1 + xrv}; \
  _Pragma("unroll") \
  for (int d8 = 0; d8 < 8; ++d8) { \
    f32x2 e2 = __builtin_shufflevector(E, E, 0, 1); \
    switch (d8) { \
      case 0: e2 = __builtin_shufflevector(E, E, 0, 1); break; \
      case 1: e2 = __builtin_shufflevector(E, E, 2, 3); break; \
      case 2: e2 = __builtin_shufflevector(E, E, 4, 5); break; \
      case 3: e2 = __builtin_shufflevector(E, E, 6, 7); break; \
      case 4: e2 = __builtin_shufflevector(E, E, 8, 9); break; \
      case 5: e2 = __builtin_shufflevector(E, E, 10, 11); break; \
      case 6: e2 = __builtin_shufflevector(E, E, 12, 13); break; \
      case 7: e2 = __builtin_shufflevector(E, E, 14, 15); break; \
    } \
    t += e2 * (f32x2){we[d8], we[d8]};            /* v_pk_fma_f32 */ \
  } \
  t = __builtin_elementwise_max(t, t * 0.2f);     /* v_pk_mul + v_pk_max */ \
  t *= (f32x2){attv, attv}; \
  t = reduce32_2(t); \
  const float e0 = exp2_raw(t.x), e1 = exp2_raw(t.y); \
  acc += (f32x2){e0, e1} * (f32x2){x0, x1};       /* v_pk_fma_f32 */ \
  den += (f32x2){e0, e1}; \
} while (0)

__global__ __launch_bounds__(256, 4) void edge_k(
    const int* __restrict__ rowptr2, const int* __restrict__ cnt,
    const int* __restrict__ src_g, const float* __restrict__ ea_g,
    const float* __restrict__ xl, const float* __restrict__ xr,
    const float* __restrict__ att_x, const float* __restrict__ att_h,
    const float* __restrict__ We_x, const float* __restrict__ We_h,
    float* __restrict__ acc_b, float* __restrict__ den_b) {
  const int lane = threadIdx.x & 63;
  const int wid = threadIdx.x >> 6;
  // bijective XCD swizzle for arbitrary grid size (m204 form)
  const int nwg = gridDim.x;
  const int bid = blockIdx.x;
  const int q = nwg >> 3, r = nwg & 7;
  const int xcd = bid & 7;
  const int swz = (xcd < r ? xcd * (q + 1) : r * (q + 1) + (xcd - r) * q) + (bid >> 3);
  const int w = __builtin_amdgcn_readfirstlane(swz * 4 + wid);
  const int bk = w / NN;          // conv index (scalar); 0..3 at t=0, 0..7 otherwise
  const int d = w - bk * NN;      // dst node (scalar)
  const int k = bk & 3;
  const bool isx = (bk < 4);

  const float xrv = xr[((size_t)bk * NN + d) * HD + lane];
  const float attv = (isx ? att_x : att_h)[k * HD + lane] * 1.44269504088896f;  // fold log2e
  const float* Wep = (isx ? We_x : We_h) + (size_t)k * DE * HD;
  float we[DE];
#pragma unroll
  for (int dd = 0; dd < DE; ++dd) we[dd] = Wep[dd * HD + lane];
  const float* xlb = xl + (size_t)bk * NN * HD;
  const f32x16* pea = reinterpret_cast<const f32x16*>(ea_g);

  const int rp0 = rowptr2[d];
  const int base2 = 2 * rp0;
  const int total = cnt[d] + 1;   // edges + self loop
  const int npair = total >> 1;
  f32x2 acc = (f32x2){0.f, 0.f}, den = (f32x2){0.f, 0.f};

  int j2 = 0;
  for (; j2 + 2 <= npair; j2 += 2) { PAIR(j2); PAIR(j2 + 1); }
  if (j2 < npair) PAIR(j2);

  if (total & 1) {                // odd tail: last edge, comp 0 of pair npair
    const int s = src_g[base2 + total - 1];
    const float xv = xlb[(size_t)s * HD + lane];
    const float* eb = ea_g + (size_t)(rp0 + npair) * 16;   // comp 0, stride 2
    float t = xv + xrv;
#pragma unroll
    for (int dd = 0; dd < DE; ++dd) t = fmaf(eb[2 * dd], we[dd], t);
    t = fmaxf(t, 0.2f * t) * attv;
    f32x2 tp = (f32x2){t, 0.f};
    tp = reduce32_2(tp);
    const float ex = exp2_raw(tp.x);
    acc.x = fmaf(ex, xv, acc.x);
    den.x += ex;
  }

  acc_b[((size_t)bk * NN + d) * HD + lane] = acc.x + acc.y;
  if ((lane & 31) == 0) den_b[((size_t)bk * NN + d) * 2 + (lane >> 5)] = den.x + den.y;
}

// ---------------- combine: LSTM gates + LayerNorm; 4 nodes per block ----------------

template <int T0>
__global__ __launch_bounds__(256, 8) void combine_k(
    const float* __restrict__ acc_b, const float* __restrict__ den_b,
    const float* __restrict__ bias_x, const float* __restrict__ bias_h,
    const float* __restrict__ bl_h,
    const float* __restrict__ ln_w, const float* __restrict__ ln_b,
    float* __restrict__ h, float* __restrict__ c) {
  int n = blockIdx.x * 4 + (threadIdx.x >> 6);
  int lane = threadIdx.x & 63;
  if (n >= NN) return;
  int head = lane >> 5;
  float g4[4];
#pragma unroll
  for (int k = 0; k < 4; ++k) {
    float ax = acc_b[((size_t)k * NN + n) * HD + lane];
    float dx = den_b[((size_t)k * NN + n) * 2 + head];
    float gh;
    if (T0) {
      gh = bl_h[k * HD + lane] + bias_h[k * HD + lane];
    } else {
      float ah = acc_b[((size_t)(k + 4) * NN + n) * HD + lane];
      float dh = den_b[((size_t)(k + 4) * NN + n) * 2 + head];
      gh = ah / dh + bias_h[k * HD + lane];
    }
    g4[k] = ax / dx + bias_x[k * HD + lane] + gh;
  }
  float iv = 1.f / (1.f + __expf(-g4[0]));
  float fv = 1.f / (1.f + __expf(-g4[1]));
  float ov = 1.f / (1.f + __expf(-g4[2]));
  float gv = tanhf(g4[3]);
  float cn;
  if (T0) {
    cn = iv * gv;
  } else {
    float cold = c[(size_t)n * HD + lane];
    cn = fv * cold + iv * gv;
  }
  float nt = ov * tanhf(cn);
  float mu = nt;
#pragma unroll
  for (int o = 32; o >= 1; o >>= 1) mu += __shfl_xor(mu, o, 64);
  mu *= (1.f / 64.f);
  float df = nt - mu;
  float v2 = df * df;
#pragma unroll
  for (int o = 32; o >= 1; o >>= 1) v2 += __shfl_xor(v2, o, 64);
  v2 *= (1.f / 64.f);
  float hn = df * rsqrtf(v2 + 1e-5f) * ln_w[lane] + ln_b[lane];
  c[(size_t)n * HD + lane] = cn;
  h[(size_t)n * HD + lane] = hn;
}

// ---------------- output MLP: gelu(h@w1+b1)@w2+b2; 4 nodes per block ----------------

__global__ __launch_bounds__(256) void out_k(const float* __restrict__ h,
                                             const float* __restrict__ w1, const float* __restrict__ b1,
                                             const float* __restrict__ w2, const float* __restrict__ b2,
                                             float* __restrict__ out) {
  int wv = threadIdx.x >> 6, j = threadIdx.x & 63;
  int n = blockIdx.x * 4 + wv;
  __shared__ float hsm[4][HD];
  __shared__ float zs[4][HD];
  if (n < NN) hsm[wv][j] = h[(size_t)n * HD + j];
  __syncthreads();
  float a = b1[j];
  for (int kk = 0; kk < HD; ++kk) a += hsm[wv][kk] * w1[kk * HD + j];
  zs[wv][j] = 0.5f * a * (1.f + erff(a * 0.70710678118654752f));
  __syncthreads();
  if (n < NN && j < OD) {
    float o = b2[j];
    for (int kk = 0; kk < HD; ++kk) o += zs[wv][kk] * w2[kk * OD + j];
    out[(size_t)n * OD + j] = o;
  }
}

// ---------------- host orchestration ----------------

extern "C" void kernel_launch(void* const* d_in, const int* in_sizes, int n_in,
                              void* d_out, int out_size, void* d_ws, size_t ws_size,
                              hipStream_t stream) {
  const float* x_seq   = (const float*)d_in[0];
  const float* edge_attr = (const float*)d_in[1];
  const int*   ei      = (const int*)d_in[2];
  const float* Wl_x    = (const float*)d_in[3];
  const float* bl_x    = (const float*)d_in[4];
  const float* Wr_x    = (const float*)d_in[5];
  const float* br_x    = (const float*)d_in[6];
  const float* We_x    = (const float*)d_in[7];
  const float* att_x   = (const float*)d_in[8];
  const float* bias_x  = (const float*)d_in[9];
  const float* Wl_h    = (const float*)d_in[10];
  const float* bl_h    = (const float*)d_in[11];
  const float* Wr_h    = (const float*)d_in[12];
  const float* br_h    = (const float*)d_in[13];
  const float* We_h    = (const float*)d_in[14];
  const float* att_h   = (const float*)d_in[15];
  const float* bias_h  = (const float*)d_in[16];
  const float* ln_w    = (const float*)d_in[17];
  const float* ln_b    = (const float*)d_in[18];
  const float* w1      = (const float*)d_in[19];
  const float* b1      = (const float*)d_in[20];
  const float* w2      = (const float*)d_in[21];
  const float* b2      = (const float*)d_in[22];
  float* out = (float*)d_out;

  const int PAIR_CAP = EE / 2 + NN + 64;   // sum of ceil((deg+1)/2) upper bound

  char* p = (char*)d_ws;
  size_t off = 0;
  auto take = [&](size_t bytes) -> char* {
    char* r = p + off;
    off += (bytes + 255) & ~(size_t)255;
    return r;
  };
  // zero-span buffers first (only cnt, cursor need zeroing)
  int*   cnt      = (int*)take(NN * sizeof(int));
  int*   cursor   = (int*)take(NN * sizeof(int));
  size_t zero_bytes = off;                       // 256-aligned, float4-divisible
  float* hbuf     = (float*)take((size_t)NN * HD * sizeof(float));
  float* cbuf     = (float*)take((size_t)NN * HD * sizeof(float));
  int*   rowptr2  = (int*)take((NN + 1) * sizeof(int));
  int*   src_g    = (int*)take((size_t)PAIR_CAP * 2 * sizeof(int));
  float* ea_g     = (float*)take((size_t)PAIR_CAP * 16 * sizeof(float));
  float* xl       = (float*)take((size_t)8 * NN * HD * sizeof(float));
  float* xr       = (float*)take((size_t)8 * NN * HD * sizeof(float));
  float* acc_b    = (float*)take((size_t)8 * NN * HD * sizeof(float));
  float* den_b    = (float*)take((size_t)8 * NN * 2 * sizeof(float));

  const int n4 = (int)(zero_bytes / 16);
  zero_k<<<40, 256, 0, stream>>>((float4*)d_ws, n4);
  hist_k<<<(EE + 255) / 256, 256, 0, stream>>>(ei, cnt);
  scan_k<<<1, 1024, 0, stream>>>(cnt, rowptr2);
  scatter_k<<<(EE + 255) / 256, 256, 0, stream>>>(ei, rowptr2, cursor, src_g, edge_attr, ea_g);
  selfmean_k<<<(NN + 3) / 4, 256, 0, stream>>>(rowptr2, cnt, src_g, ea_g);

  for (int t = 0; t < TT; ++t) {
    const float* x_t = x_seq + (size_t)t * NN * FI;
    const int nconv = (t == 0) ? 4 : 8;   // h==0 at t=0: h-branch GAT is constant
    node_k<<<dim3(NN / 8, t == 0 ? 1 : 2), 256, 0, stream>>>(
        x_t, hbuf, Wl_x, bl_x, Wr_x, br_x, Wl_h, bl_h, Wr_h, br_h, xl, xr);
    edge_k<<<nconv * NN / 4, 256, 0, stream>>>(rowptr2, cnt, src_g, ea_g, xl, xr,
                                               att_x, att_h, We_x, We_h, acc_b, den_b);
    if (t == 0)
      combine_k<1><<<(NN + 3) / 4, 256, 0, stream>>>(acc_b, den_b, bias_x, bias_h, bl_h,
                                                     ln_w, ln_b, hbuf, cbuf);
    else
      combine_k<0><<<(NN + 3) / 4, 256, 0, stream>>>(acc_b, den_b, bias_x, bias_h, bl_h,
                                                     ln_w, ln_b, hbuf, cbuf);
  }
  out_k<<<(NN + 3) / 4, 256, 0, stream>>>(hbuf, w1, b1, w2, b2, out);
}